// Round 6
// baseline (406.945 us; speedup 1.0000x reference)
//
#include <hip/hip_runtime.h>
#include <hip/hip_bf16.h>

#define NROWS 8192
typedef unsigned short u16;
typedef short bf16x8 __attribute__((ext_vector_type(8)));
typedef float f32x4 __attribute__((ext_vector_type(4)));

__device__ __forceinline__ u16 f2b(float f) {   // fp32 -> bf16 RNE (finite data)
    unsigned u = __float_as_uint(f);
    unsigned r = (u + 0x7fffu + ((u >> 16) & 1u)) >> 16;
    return (u16)r;
}

template<int MODE> __device__ __forceinline__ float actf(float v) {
    if constexpr (MODE == 1) return fmaxf(v, 0.f);
    else if constexpr (MODE == 2) return v > 0.f ? v : 0.2f * v;
    else return v;
}

// ---------------------------------------------------------------------------
// Weight folds, parallelized. ws layout (floats):
//   WA[128*64]@0  bA[64]@8192  cA[64]@8256  WB[64*16]@8320  bB[16]@9344
//   cB[16]@9360  T2[64*32]@9376  v1[128]@11424  v2[32]@11552  T1[128*128]@16384
// ---------------------------------------------------------------------------
__global__ __launch_bounds__(256) void fold1(
    const float* __restrict__ W1, const float* __restrict__ b1,
    const float* __restrict__ Wg1,
    const float* __restrict__ W2, const float* __restrict__ b2,
    const float* __restrict__ Wg2, float* __restrict__ ws) {
    float* T2 = ws + 9376;
    float* v1 = ws + 11424;
    float* v2 = ws + 11552;
    float* T1 = ws + 16384;
    const int tid = threadIdx.x, b = blockIdx.x;
    if (b < 16) {                       // T1 = W1 @ Wg1
        int i = b * 8 + (tid >> 5), j4 = (tid & 31) << 2;
        float4 acc = {0, 0, 0, 0};
        for (int k = 0; k < 128; ++k) {
            float a = W1[i * 128 + k];
            float4 g = *(const float4*)&Wg1[k * 128 + j4];
            acc.x += a * g.x; acc.y += a * g.y; acc.z += a * g.z; acc.w += a * g.w;
        }
        *(float4*)&T1[i * 128 + j4] = acc;
    } else if (b == 16) {
        if (tid < 128) {
            float s = 0;
            for (int k = 0; k < 128; ++k) s += b1[k] * Wg1[k * 128 + tid];
            v1[tid] = s;
        } else if (tid < 160) {
            int j = tid - 128;
            float s = 0;
            for (int k = 0; k < 32; ++k) s += b2[k] * Wg2[k * 32 + j];
            v2[j] = s;
        }
    } else {                            // T2 = W2 @ Wg2
        for (int o4 = tid; o4 < 64 * 8; o4 += 256) {
            int i = o4 >> 3, j4 = (o4 & 7) << 2;
            float4 acc = {0, 0, 0, 0};
            for (int k = 0; k < 32; ++k) {
                float a = W2[i * 32 + k];
                float4 g = *(const float4*)&Wg2[k * 32 + j4];
                acc.x += a * g.x; acc.y += a * g.y; acc.z += a * g.z; acc.w += a * g.w;
            }
            *(float4*)&T2[i * 32 + j4] = acc;
        }
    }
}

__global__ __launch_bounds__(256) void fold2(
    const float* __restrict__ Wm1, const float* __restrict__ bm1,
    const float* __restrict__ bg1,
    const float* __restrict__ W3, const float* __restrict__ b3,
    const float* __restrict__ bg2, float* __restrict__ ws) {
    float* WA = ws + 0;
    float* bA = ws + 8192;
    float* cA = ws + 8256;
    float* WB = ws + 8320;
    float* bB = ws + 9344;
    float* cB = ws + 9360;
    const float* T2 = ws + 9376;
    const float* v1 = ws + 11424;
    const float* v2 = ws + 11552;
    const float* T1 = ws + 16384;
    const int tid = threadIdx.x, b = blockIdx.x;
    if (b < 8) {                        // WA = T1 @ Wm1
        int i = b * 16 + (tid >> 4), j4 = (tid & 15) << 2;
        float4 acc = {0, 0, 0, 0};
        for (int k = 0; k < 128; ++k) {
            float a = T1[i * 128 + k];
            float4 g = *(const float4*)&Wm1[k * 64 + j4];
            acc.x += a * g.x; acc.y += a * g.y; acc.z += a * g.z; acc.w += a * g.w;
        }
        *(float4*)&WA[i * 64 + j4] = acc;
    } else if (b == 8) {
        if (tid < 64) {
            float s = 0, c = 0;
            for (int k = 0; k < 128; ++k) {
                s += v1[k] * Wm1[k * 64 + tid];
                c += bg1[k] * Wm1[k * 64 + tid];
            }
            bA[tid] = s; cA[tid] = c + bm1[tid];
        } else if (tid < 80) {
            int j = tid - 64;
            float s = 0, c = 0;
            for (int k = 0; k < 32; ++k) {
                s += v2[k] * W3[k * 16 + j];
                c += bg2[k] * W3[k * 16 + j];
            }
            bB[j] = s; cB[j] = c + b3[j];
        }
    } else {                            // WB = T2 @ W3
        int i = tid >> 2, j4 = (tid & 3) << 2;
        float4 acc = {0, 0, 0, 0};
        for (int k = 0; k < 32; ++k) {
            float a = T2[i * 32 + k];
            float4 g = *(const float4*)&W3[k * 16 + j4];
            acc.x += a * g.x; acc.y += a * g.y; acc.z += a * g.z; acc.w += a * g.w;
        }
        *(float4*)&WB[i * 16 + j4] = acc;
    }
}

// ---------------------------------------------------------------------------
// Small row GEMM: out = AOUT( AIN(in)[N,K] @ W[K,M] + bias )
// OUTT=0: fp32 row-major [N,M].  OUTT=1: bf16 TRANSPOSED [M][NROWS] (S^T).
// ---------------------------------------------------------------------------
template<int K, int M, int AIN, int AOUT, int OUTT>
__global__ __launch_bounds__(256) void gemm_rows(
    const float* __restrict__ in, const float* __restrict__ W,
    const float* __restrict__ bias, void* __restrict__ outv) {
    constexpr int RB = 32;
    constexpr int TNs = (M >= 64) ? 4 : 2;
    constexpr int TXs = M / TNs;
    constexpr int TYs = 256 / TXs;
    constexpr int TMs = RB / TYs;
    static_assert(TMs >= 1 && TMs * TYs == RB, "bad cfg");
    __shared__ float in_t[K][RB + 4];
    __shared__ float w_s[K * M];
    __shared__ float bias_s[M];
    const int tid = threadIdx.x;
    const int b0 = blockIdx.x * RB;
    constexpr int K4 = K / 4;
    for (int g = tid; g < RB * K4; g += 256) {
        int r = g / K4, c4 = g % K4;
        float4 v = *(const float4*)&in[(size_t)(b0 + r) * K + c4 * 4];
        v.x = actf<AIN>(v.x); v.y = actf<AIN>(v.y);
        v.z = actf<AIN>(v.z); v.w = actf<AIN>(v.w);
        in_t[c4 * 4 + 0][r] = v.x;
        in_t[c4 * 4 + 1][r] = v.y;
        in_t[c4 * 4 + 2][r] = v.z;
        in_t[c4 * 4 + 3][r] = v.w;
    }
    for (int g = tid; g < K * M / 4; g += 256)
        ((float4*)w_s)[g] = ((const float4*)W)[g];
    if (tid < M) bias_s[tid] = bias ? bias[tid] : 0.f;
    __syncthreads();

    const int tx = tid % TXs, ty = tid / TXs;
    const int c0 = tx * TNs, r0 = ty * TMs;
    float acc[TMs][TNs] = {};
    for (int k = 0; k < K; ++k) {
        float a[TMs];
#pragma unroll
        for (int m = 0; m < TMs; ++m) a[m] = in_t[k][r0 + m];
        float w[TNs];
#pragma unroll
        for (int n = 0; n < TNs; ++n) w[n] = w_s[k * M + c0 + n];
#pragma unroll
        for (int m = 0; m < TMs; ++m)
#pragma unroll
            for (int n = 0; n < TNs; ++n) acc[m][n] += a[m] * w[n];
    }
#pragma unroll
    for (int m = 0; m < TMs; ++m) {
        float vres[TNs];
#pragma unroll
        for (int n = 0; n < TNs; ++n) vres[n] = actf<AOUT>(acc[m][n] + bias_s[c0 + n]);
        if constexpr (OUTT == 0) {
            float* op = &((float*)outv)[(size_t)(b0 + r0 + m) * M + c0];
            if constexpr (TNs == 4) { float4 o4 = {vres[0], vres[1], vres[2], vres[3]}; *(float4*)op = o4; }
            else                    { float2 o2 = {vres[0], vres[1]}; *(float2*)op = o2; }
        } else {
            u16* ot = (u16*)outv;
#pragma unroll
            for (int n = 0; n < TNs; ++n)
                ot[(size_t)(c0 + n) * NROWS + (b0 + r0 + m)] = f2b(vres[n]);
        }
    }
}

// ---------------------------------------------------------------------------
// Fused med chain (row-local): per block of 32 rows:
//   h1=lrelu(gA); h2=lrelu(h1@Wm2+bm2); h3=lrelu(h2@Wm3+bm3);
//   h4=relu(h3@Wm4+bm4) -> global; s2=h4@Wgh -> St (bf16 transposed)
// ---------------------------------------------------------------------------
template<int K, int M, int AOUT, int OMODE>  // OMODE 0: panel; 1: panel+global; 2: St only
__device__ __forceinline__ void layer_step(
    const float (*pin)[33], const float* w, const float* bias,
    float (*pout)[33], float* gout, u16* stout, int b0, int tid) {
    constexpr int TXs = M / 4;
    constexpr int TYs = 256 / TXs;
    constexpr int TMs = 32 / TYs;
    const int tx = tid % TXs, ty = tid / TXs;
    const int c0 = tx * 4, r0 = ty * TMs;
    float acc[TMs][4] = {};
    for (int k = 0; k < K; ++k) {
        float4 wv = *(const float4*)&w[k * M + c0];
#pragma unroll
        for (int m = 0; m < TMs; ++m) {
            float a = pin[k][r0 + m];
            acc[m][0] += a * wv.x; acc[m][1] += a * wv.y;
            acc[m][2] += a * wv.z; acc[m][3] += a * wv.w;
        }
    }
#pragma unroll
    for (int m = 0; m < TMs; ++m) {
        float v[4];
#pragma unroll
        for (int n = 0; n < 4; ++n) {
            float bv = bias ? bias[c0 + n] : 0.f;
            v[n] = actf<AOUT>(acc[m][n] + bv);
        }
        if constexpr (OMODE != 2) {
#pragma unroll
            for (int n = 0; n < 4; ++n) pout[c0 + n][r0 + m] = v[n];
        }
        if constexpr (OMODE == 1) {
            float4 o = {v[0], v[1], v[2], v[3]};
            *(float4*)&gout[(size_t)(b0 + r0 + m) * M + c0] = o;
        }
        if constexpr (OMODE == 2) {
#pragma unroll
            for (int n = 0; n < 4; ++n)
                stout[(size_t)(c0 + n) * NROWS + (b0 + r0 + m)] = f2b(v[n]);
        }
    }
}

__global__ __launch_bounds__(256) void med_chain(
    const float* __restrict__ gA,
    const float* __restrict__ Wm2, const float* __restrict__ bm2,
    const float* __restrict__ Wm3, const float* __restrict__ bm3,
    const float* __restrict__ Wm4, const float* __restrict__ bm4,
    const float* __restrict__ Wgh,
    float* __restrict__ h4, u16* __restrict__ St) {
    __shared__ __align__(16) float P0[64][33];
    __shared__ __align__(16) float P1[128][33];
    __shared__ __align__(16) float P2[64][33];
    __shared__ __align__(16) float wb0[8192];
    __shared__ __align__(16) float wb1[8192];
    __shared__ float bias128[128], bias64a[64], bias64b[64];
    const int tid = threadIdx.x;
    const int b0 = blockIdx.x * 32;

    // phase 0: load input panel (lrelu) + Wm2/Wm3 + biases
    for (int g = tid; g < 32 * 16; g += 256) {
        int r = g >> 4, c4 = g & 15;
        float4 v = *(const float4*)&gA[(size_t)(b0 + r) * 64 + c4 * 4];
        P0[c4 * 4 + 0][r] = actf<2>(v.x);
        P0[c4 * 4 + 1][r] = actf<2>(v.y);
        P0[c4 * 4 + 2][r] = actf<2>(v.z);
        P0[c4 * 4 + 3][r] = actf<2>(v.w);
    }
    for (int g = tid; g < 2048; g += 256) ((float4*)wb0)[g] = ((const float4*)Wm2)[g];
    for (int g = tid; g < 2048; g += 256) ((float4*)wb1)[g] = ((const float4*)Wm3)[g];
    if (tid < 128) bias128[tid] = bm2[tid];
    else if (tid < 192) bias64a[tid - 128] = bm3[tid - 128];
    else bias64b[tid - 192] = bm4[tid - 192];
    __syncthreads();
    // L1: P1 = lrelu(P0 @ Wm2 + bm2)   K=64 M=128
    layer_step<64, 128, 2, 0>(P0, wb0, bias128, P1, nullptr, nullptr, b0, tid);
    __syncthreads();
    // stage Wm4|Wgh into wb0 (free now) while computing L2 from wb1
    for (int g = tid; g < 1024; g += 256) ((float4*)wb0)[g] = ((const float4*)Wm4)[g];
    for (int g = tid; g < 1024; g += 256) ((float4*)(wb0 + 4096))[g] = ((const float4*)Wgh)[g];
    // L2: P2 = lrelu(P1 @ Wm3 + bm3)   K=128 M=64
    layer_step<128, 64, 2, 0>(P1, wb1, bias64a, P2, nullptr, nullptr, b0, tid);
    __syncthreads();
    // L3: P0 = relu(P2 @ Wm4 + bm4) -> also h4 global
    layer_step<64, 64, 1, 1>(P2, wb0, bias64b, P0, h4, nullptr, b0, tid);
    __syncthreads();
    // L4: St = bf16((P0 @ Wgh)^T)  (no bias)
    layer_step<64, 64, 0, 2>(P0, wb0 + 4096, nullptr, nullptr, nullptr, St, b0, tid);
}

// ---------------------------------------------------------------------------
// MFMA aggregation with explicit 2-slot register pipeline.
// MODE 0: A from Abf.  MODE 1: A = bf16(adj*dis) on the fly (NT reads) + write
// Abf.  MODE 2: on the fly, no write.
// ---------------------------------------------------------------------------
#define AGG_ISSUE(S, T) { \
    size_t ao_ = aoff + (size_t)(T) * 32; \
    if constexpr (MODE == 0) { raf##S = *(const bf16x8*)(Abf + ao_); } \
    else { \
        const f32x4* a4_ = (const f32x4*)(adj + ao_); \
        const f32x4* d4_ = (const f32x4*)(dis + ao_); \
        a0##S = __builtin_nontemporal_load(a4_); \
        a1##S = __builtin_nontemporal_load(a4_ + 1); \
        d0##S = __builtin_nontemporal_load(d4_); \
        d1##S = __builtin_nontemporal_load(d4_ + 1); \
    } \
    const u16* bB_ = Bbase + (size_t)(T) * 32; \
    _Pragma("unroll") \
    for (int ct = 0; ct < CT; ++ct) rb##S[ct] = *(const bf16x8*)(bB_ + (size_t)ct * 16 * NROWS); }

#define AGG_STEP(S, T) { \
    bf16x8 af_; \
    if constexpr (MODE == 0) { af_ = raf##S; } \
    else { \
        _Pragma("unroll") \
        for (int j = 0; j < 4; ++j) { \
            af_[j]     = (short)f2b(a0##S[j] * d0##S[j]); \
            af_[j + 4] = (short)f2b(a1##S[j] * d1##S[j]); \
        } \
        if constexpr (MODE == 1) *(bf16x8*)(Abf + aoff + (size_t)(T) * 32) = af_; \
    } \
    _Pragma("unroll") \
    for (int ct = 0; ct < CT; ++ct) \
        acc[ct] = __builtin_amdgcn_mfma_f32_16x16x32_bf16(af_, rb##S[ct], acc[ct], 0, 0, 0); }

template<int F, int MODE, int KS>
__global__ __launch_bounds__(256) void agg_mfma(
    u16* __restrict__ Abf, const float* __restrict__ adj,
    const float* __restrict__ dis, const u16* __restrict__ St,
    float* __restrict__ Pout) {
    constexpr int CT = F / 16;
    constexpr int KCH = NROWS / KS;
    constexpr int NIT = KCH / 32;
    static_assert(NIT >= 4 && (NIT & 1) == 0, "pipeline needs even NIT>=4");
    const int lane = threadIdx.x & 63;
    const int wid  = threadIdx.x >> 6;
    const int r0   = blockIdx.x * 64 + wid * 16;
    const int ky   = blockIdx.y;
    const int l15  = lane & 15;
    const int kb   = (lane >> 4) * 8;
    const int k0   = ky * KCH;
    f32x4 acc[CT] = {};
    size_t aoff = (size_t)(r0 + l15) * NROWS + k0 + kb;
    const u16* Bbase = St + (size_t)l15 * NROWS + k0 + kb;

    f32x4 a0A, a1A, d0A, d1A, a0B, a1B, d0B, d1B;
    bf16x8 rafA, rafB;
    bf16x8 rbA[CT], rbB[CT];

    AGG_ISSUE(A, 0)
    AGG_ISSUE(B, 1)
    for (int t = 0; t < NIT - 2; t += 2) {
        AGG_STEP(A, t)
        AGG_ISSUE(A, t + 2)
        AGG_STEP(B, t + 1)
        AGG_ISSUE(B, t + 3)
    }
    AGG_STEP(A, NIT - 2)
    AGG_STEP(B, NIT - 1)

    // C/D layout: col = lane&15, row = (lane>>4)*4 + i   [m89-verified]
    float* P = Pout + (size_t)ky * ((size_t)NROWS * F);
    const int rb = r0 + (lane >> 4) * 4;
#pragma unroll
    for (int ct = 0; ct < CT; ++ct)
#pragma unroll
        for (int i = 0; i < 4; ++i)
            P[(size_t)(rb + i) * F + ct * 16 + l15] = acc[ct][i];
}

// ---------------------------------------------------------------------------
// out = sum_{ky} P[ky] + bias[col] (+ res)
// ---------------------------------------------------------------------------
template<int F, int KS>
__global__ __launch_bounds__(256) void reduce_add(
    const float* __restrict__ P, const float* __restrict__ bias,
    const float* __restrict__ res, float* __restrict__ out) {
    constexpr int TOT4 = NROWS * F / 4;
    int i = blockIdx.x * 256 + threadIdx.x;
    if (i >= TOT4) return;
    constexpr size_t STR = (size_t)NROWS * F / 4;
    const float4* P4 = (const float4*)P;
    float4 s = P4[i];
#pragma unroll
    for (int k = 1; k < KS; ++k) {
        float4 t = P4[i + (size_t)k * STR];
        s.x += t.x; s.y += t.y; s.z += t.z; s.w += t.w;
    }
    float4 b = *(const float4*)&bias[(i % (F / 4)) * 4];
    s.x += b.x; s.y += b.y; s.z += b.z; s.w += b.w;
    if (res) {
        float4 r = ((const float4*)res)[i];
        s.x += r.x; s.y += r.y; s.z += r.z; s.w += r.w;
    }
    ((float4*)out)[i] = s;
}

extern "C" void kernel_launch(void* const* d_in, const int* in_sizes, int n_in,
                              void* d_out, int out_size, void* d_ws, size_t ws_size,
                              hipStream_t stream) {
    const float* x   = (const float*)d_in[0];
    const float* adj = (const float*)d_in[1];
    const float* dis = (const float*)d_in[2];
    const float* W1  = (const float*)d_in[3];
    const float* b1  = (const float*)d_in[4];
    const float* Wg1 = (const float*)d_in[5];
    const float* bg1 = (const float*)d_in[6];
    const float* Wm1 = (const float*)d_in[7];
    const float* bm1 = (const float*)d_in[8];
    const float* Wm2 = (const float*)d_in[9];
    const float* bm2 = (const float*)d_in[10];
    const float* Wm3 = (const float*)d_in[11];
    const float* bm3 = (const float*)d_in[12];
    const float* Wm4 = (const float*)d_in[13];
    const float* bm4 = (const float*)d_in[14];
    const float* Wgh = (const float*)d_in[15];
    const float* bgh = (const float*)d_in[16];
    const float* W2  = (const float*)d_in[17];
    const float* b2  = (const float*)d_in[18];
    const float* Wg2 = (const float*)d_in[19];
    const float* bg2 = (const float*)d_in[20];
    const float* W3  = (const float*)d_in[21];
    const float* b3  = (const float*)d_in[22];
    float* ws  = (float*)d_ws;
    float* out = (float*)d_out;

    constexpr int KS = 8;
    const size_t ABF_FLOATS = (size_t)NROWS * NROWS / 2;   // 128MB as floats
    const size_t BASE_FLOATS = 40960 + 262144 + (size_t)KS * 524288 + 524288 + 524288;
    const size_t NEED_PRE_BYTES = (ABF_FLOATS + BASE_FLOATS) * 4ULL;  // ~156.4MB
    const bool pre = ws_size >= NEED_PRE_BYTES;

    float* base = ws + (pre ? ABF_FLOATS : 0);
    float* wsW  = base;                       // fold area: 40960 floats
    float* St_f = wsW + 40960;                // S^T bf16 [64][8192] (shared)
    float* P    = St_f + 262144;              // partials: KS*8192*64
    float* gA   = P + (size_t)KS * 524288;    // [8192,64]
    float* h4   = gA + 524288;                // [8192,64]
    float* g2   = gA;                         // alias: gA dead after med_chain

    u16* Abf = (u16*)ws;
    u16* St  = (u16*)St_f;
    const float* WA = wsW + 0;
    const float* bA = wsW + 8192;
    const float* cA = wsW + 8256;
    const float* WB = wsW + 8320;
    const float* bB = wsW + 9344;
    const float* cB = wsW + 9360;

    fold1<<<18, 256, 0, stream>>>(W1, b1, Wg1, W2, b2, Wg2, wsW);
    fold2<<<10, 256, 0, stream>>>(Wm1, bm1, bg1, W3, b3, bg2, wsW);

    // pass 1 (fused converter): sA^T = (x @ WA + bA)^T ; gA = A@sA + cA
    gemm_rows<128, 64, 0, 0, 1><<<256, 256, 0, stream>>>(x, WA, bA, St);
    if (pre) agg_mfma<64, 1, KS><<<dim3(128, KS), 256, 0, stream>>>(Abf, adj, dis, St, P);
    else     agg_mfma<64, 2, KS><<<dim3(128, KS), 256, 0, stream>>>(nullptr, adj, dis, St, P);
    reduce_add<64, KS><<<512, 256, 0, stream>>>(P, cA, nullptr, gA);

    // fused med chain: gA -> h4 (global) + s2^T (St, bf16)
    med_chain<<<256, 256, 0, stream>>>(gA, Wm2, bm2, Wm3, bm3, Wm4, bm4, Wgh, h4, St);

    // pass 2: g2 = A@s2 + bgh + h4
    if (pre) agg_mfma<64, 0, KS><<<dim3(128, KS), 256, 0, stream>>>(Abf, nullptr, nullptr, St, P);
    else     agg_mfma<64, 2, KS><<<dim3(128, KS), 256, 0, stream>>>(nullptr, adj, dis, St, P);
    reduce_add<64, KS><<<512, 256, 0, stream>>>(P, bgh, h4, g2);

    // pass 3: sB^T = (relu(g2) @ WB + bB)^T ; out = A@sB + cB
    gemm_rows<64, 16, 1, 0, 1><<<256, 256, 0, stream>>>(g2, WB, bB, St);
    if (pre) agg_mfma<16, 0, KS><<<dim3(128, KS), 256, 0, stream>>>(Abf, nullptr, nullptr, St, P);
    else     agg_mfma<16, 2, KS><<<dim3(128, KS), 256, 0, stream>>>(nullptr, adj, dis, St, P);
    reduce_add<16, KS><<<128, 256, 0, stream>>>(P, cB, nullptr, out);
}